// Round 10
// baseline (1356.965 us; speedup 1.0000x reference)
//
#include <hip/hip_runtime.h>
#include <hip/hip_bf16.h>

#define N_NODES  60000
#define N_EDGES  240000
#define N_REL    4
#define N_GRAPHS 128
#define D_IN     768
#define D_H      256
#define N_LAYERS 6
#define M_PAD    60032            // 469 * 128
#define N_TOT    1280             // GEMM out: 256 root + 4*256 per-relation msg

static inline int cdiv(int a, int b) { return (a + b - 1) / b; }

typedef __attribute__((ext_vector_type(8))) short short8;
typedef __attribute__((ext_vector_type(4))) float f32x4;

__device__ __forceinline__ float bf2f(unsigned short u) {
    union { unsigned int i; float f; } c; c.i = ((unsigned int)u) << 16; return c.f;
}
__device__ __forceinline__ float bflo(unsigned int u) {
    union { unsigned int i; float f; } c; c.i = u << 16; return c.f;
}
__device__ __forceinline__ float bfhi(unsigned int u) {
    union { unsigned int i; float f; } c; c.i = u & 0xffff0000u; return c.f;
}
__device__ __forceinline__ unsigned short f2bf(float f) {
    union { float f; unsigned int i; } c; c.f = f;
    unsigned int i = c.i;
    unsigned int r = (i + 0x7FFFu + ((i >> 16) & 1u)) >> 16;   // RNE
    return (unsigned short)r;
}

__device__ __forceinline__ void gload16(const void* g, void* l) {
    __builtin_amdgcn_global_load_lds((const __attribute__((address_space(1))) void*)g,
                                     (__attribute__((address_space(3))) void*)l, 16, 0, 0);
}

// ---------------------------------------------------------------------------
// Transform GEMM (proven 128x256 tile, ~154 us @ K=768, ~52 us @ K=256):
// A[M_PAD,K] bf16 @ Wt[1280,K]^T -> root[M,256] (+bias) and per-relation
// msg SLABS msg[r][M,256].  Double-buffered LDS; XCD-chunked remap.
// grid = 8*295 (15 idle).
// ---------------------------------------------------------------------------
__global__ __launch_bounds__(512) void gemm_l0(
    const unsigned short* __restrict__ A,
    const unsigned short* __restrict__ Bt,
    const float* __restrict__ bias,
    unsigned short* __restrict__ out_root,
    unsigned short* __restrict__ out_msg,     // [4][M_PAD][256] slabs
    int K)
{
    __shared__ __align__(16) unsigned short S[2][(128 + 256) * 32];   // 2 x 24576 B

    const int bid  = blockIdx.x;
    const int xcd  = bid & 7;
    const int j    = bid >> 3;                       // 0..294
    const int nrow = (xcd < 5) ? 59 : 58;
    const int rbase = (xcd < 5) ? xcd * 59 : 295 + (xcd - 5) * 58;
    const int rr = j / 5, cc = j % 5;
    if (rr >= nrow) return;
    const int bm = (rbase + rr) * 128;
    const int bn = cc * 256;

    const int tid  = threadIdx.x;
    const int wave = tid >> 6, lane = tid & 63;
    const int wm = (wave & 1) * 64, wn = (wave >> 1) * 64;

    const int lr = lane >> 2;
    const int kg = ((lane & 3) ^ ((lr ^ (lr >> 2)) & 3)) * 8;   // swizzled k-chunk
    const unsigned short* gsrc[3];
    int ldoff[3];
    #pragma unroll
    for (int t = 0; t < 3; ++t) {
        int g = wave * 3 + t;
        if (g < 8) {
            gsrc[t] = A + (size_t)(bm + g * 16 + lr) * K + kg;
            ldoff[t] = g * 512;                       // As region: shorts 0..4095
        } else {
            gsrc[t] = Bt + (size_t)(bn + (g - 8) * 16 + lr) * K + kg;
            ldoff[t] = 4096 + (g - 8) * 512;          // Bs region: shorts 4096..12287
        }
    }

    f32x4 acc[4][4] = {};
    const int fr = lane & 15;
    const int qsw = (((lane >> 4) ^ fr ^ (fr >> 2)) & 3) * 8;

    const int nstep = K >> 5;                         // 24 (L0) or 8 (mid)
    gload16(gsrc[0], S[0] + ldoff[0]);
    gload16(gsrc[1], S[0] + ldoff[1]);
    gload16(gsrc[2], S[0] + ldoff[2]);
    __syncthreads();                                  // slice 0 staged

    #pragma unroll 1
    for (int t = 0; t < nstep; ++t) {
        if (t + 1 < nstep) {                          // stage ahead into alt buffer
            unsigned short* nb = S[(t + 1) & 1];
            gload16(gsrc[0] + (t + 1) * 32, nb + ldoff[0]);
            gload16(gsrc[1] + (t + 1) * 32, nb + ldoff[1]);
            gload16(gsrc[2] + (t + 1) * 32, nb + ldoff[2]);
        }
        const unsigned short* cur = S[t & 1];
        short8 a[4], b[4];
        #pragma unroll
        for (int q = 0; q < 4; ++q) {
            a[q] = *(const short8*)&cur[(wm + q * 16 + fr) * 32 + qsw];
            b[q] = *(const short8*)&cur[4096 + (wn + q * 16 + fr) * 32 + qsw];
        }
        #pragma unroll
        for (int mt = 0; mt < 4; ++mt)
            #pragma unroll
            for (int nt = 0; nt < 4; ++nt)
                acc[mt][nt] = __builtin_amdgcn_mfma_f32_16x16x32_bf16(
                    a[mt], b[nt], acc[mt][nt], 0, 0, 0);
        __syncthreads();   // drains vmcnt(0): stage(t+1) done; reads of S[(t+1)&1] done
    }

    const bool is_root = (bn == 0);   // block-uniform
    #pragma unroll
    for (int mt = 0; mt < 4; ++mt) {
        #pragma unroll
        for (int nt = 0; nt < 4; ++nt) {
            int col = bn + wn + nt * 16 + fr;
            float bv = bias[col];
            #pragma unroll
            for (int r = 0; r < 4; ++r) {
                int row = bm + wm + mt * 16 + ((lane >> 4) << 2) + r;
                float v = acc[mt][nt][r] + bv;
                if (is_root) {
                    out_root[(size_t)row * 256 + col] = f2bf(v);
                } else {
                    int plane = (col >> 8) - 1;                    // relation 0..3
                    out_msg[((size_t)plane * M_PAD + row) * 256 + (col & 255)] = f2bf(v);
                }
            }
        }
    }
}

// ---------------------------------------------------------------------------
// Aggregate, relation-wave version: ONE BLOCK PER NODE, one wave per relation.
// Each wave gathers its own (node, r) CSR segment from its 31 MB slab
// (chain length ~= mean degree 1, vs ~4-8 in the 1-wave-per-node version),
// scales by inv-degree, then a 3 KB LDS reduction + root + bias'd ReLU store.
// 4x the wave-level parallelism, 1/4 the serial chain -> latency-bound fix.
// ---------------------------------------------------------------------------
__global__ __launch_bounds__(256) void aggregate_rw(
    const unsigned short* __restrict__ rootb,   // [M_PAD,256]
    const unsigned short* __restrict__ msg,     // [4][M_PAD,256] slabs
    const int* __restrict__ rp4, const int* __restrict__ e_srcs,
    const float* __restrict__ inv4,
    unsigned short* __restrict__ h_out)         // [M_PAD,256]
{
    __shared__ float red[3 * 256];

    const int node = blockIdx.x;                // grid = N_NODES exactly
    const int wave = threadIdx.x >> 6;          // relation 0..3
    const int lane = threadIdx.x & 63;

    const int lo = rp4[node * 4 + wave];
    const int hi = rp4[node * 4 + wave + 1];
    const unsigned short* slab = msg + (size_t)wave * M_PAD * 256;

    float4 s = make_float4(0.f, 0.f, 0.f, 0.f);
    for (int e = lo; e < hi; ++e) {
        int src = e_srcs[e];
        ushort4 m = *(const ushort4*)&slab[(size_t)src * 256 + lane * 4];
        s.x += bf2f(m.x); s.y += bf2f(m.y);
        s.z += bf2f(m.z); s.w += bf2f(m.w);
    }
    const float f = inv4[node * 4 + wave];
    s.x *= f; s.y *= f; s.z *= f; s.w *= f;

    if (wave != 0) *(float4*)&red[(wave - 1) * 256 + lane * 4] = s;
    __syncthreads();

    if (wave == 0) {
        ushort4 rt = *(const ushort4*)&rootb[(size_t)node * 256 + lane * 4];
        float4 r0 = *(const float4*)&red[0 * 256 + lane * 4];
        float4 r1 = *(const float4*)&red[1 * 256 + lane * 4];
        float4 r2 = *(const float4*)&red[2 * 256 + lane * 4];
        float4 acc;
        acc.x = bf2f(rt.x) + s.x + r0.x + r1.x + r2.x;
        acc.y = bf2f(rt.y) + s.y + r0.y + r1.y + r2.y;
        acc.z = bf2f(rt.z) + s.z + r0.z + r1.z + r2.z;
        acc.w = bf2f(rt.w) + s.w + r0.w + r1.w + r2.w;
        ushort4 o;
        o.x = f2bf(fmaxf(acc.x, 0.f));
        o.y = f2bf(fmaxf(acc.y, 0.f));
        o.z = f2bf(fmaxf(acc.z, 0.f));
        o.w = f2bf(fmaxf(acc.w, 0.f));
        *(ushort4*)&h_out[(size_t)node * 256 + lane * 4] = o;
    }
}

// ---------------------------------------------------------------------------
// Prep kernels
// ---------------------------------------------------------------------------
__global__ void convert_x(const float* __restrict__ x, unsigned short* __restrict__ xb) {
    size_t i = ((size_t)blockIdx.x * 256 + threadIdx.x) * 4;
    if (i >= (size_t)M_PAD * D_IN) return;
    ushort4 o;
    if (i < (size_t)N_NODES * D_IN) {
        float4 v = *(const float4*)&x[i];
        o.x = f2bf(v.x); o.y = f2bf(v.y); o.z = f2bf(v.z); o.w = f2bf(v.w);
    } else {
        o.x = o.y = o.z = o.w = 0;
    }
    *(ushort4*)&xb[i] = o;
}

__global__ void pack_w0(const float* __restrict__ root0, const float* __restrict__ w0,
                        unsigned short* __restrict__ Wt0) {
    int idx = blockIdx.x * 256 + threadIdx.x;            // Wt0[n][k], [1280 x 768]
    if (idx >= N_TOT * D_IN) return;
    int k = idx % D_IN, n = idx / D_IN;
    float v = (n < 256) ? root0[k * 256 + n]
                        : w0[(((n >> 8) - 1) * D_IN + k) * 256 + (n & 255)];
    Wt0[idx] = f2bf(v);
}

// WtR[l][n][k], n in [0,1280), k in [0,256):
//   n<256  -> root_rest[l][k][n]
//   n>=256 -> w_rest[l][(n>>8)-1][k][n&255]
__global__ void pack_wr(const float* __restrict__ root_rest, const float* __restrict__ w_rest,
                        unsigned short* __restrict__ WtR) {
    int idx = blockIdx.x * 256 + threadIdx.x;
    if (idx >= 5 * N_TOT * 256) return;
    int k = idx & 255; int t = idx >> 8; int n = t % N_TOT; int l = t / N_TOT;
    float v = (n < 256)
        ? root_rest[(l * 256 + k) * 256 + n]
        : w_rest[(((l * 4 + ((n >> 8) - 1)) * 256) + k) * 256 + (n & 255)];
    WtR[idx] = f2bf(v);
}

// eb[6][1280]: l=0 -> [b0 | 0...]; l>=1 -> [b_rest[l-1] | 0...]
__global__ void build_bias_all(const float* __restrict__ b0, const float* __restrict__ b_rest,
                               float* __restrict__ eb) {
    int i = blockIdx.x * 256 + threadIdx.x;
    if (i >= 6 * N_TOT) return;
    int l = i / N_TOT, c = i % N_TOT;
    float v = 0.f;
    if (c < 256) v = (l == 0) ? b0[c] : b_rest[(l - 1) * 256 + c];
    eb[i] = v;
}

// ---------------------------------------------------------------------------
// (dst, rel)-sorted CSR over 4*N segments
// ---------------------------------------------------------------------------
__global__ void deg4_count(const int* __restrict__ dst, const int* __restrict__ rel,
                           int* __restrict__ deg4, int E) {
    int e = blockIdx.x * 256 + threadIdx.x;
    if (e < E) atomicAdd(&deg4[dst[e] * 4 + rel[e]], 1);
}

__global__ void invert4(const int* __restrict__ deg4, float* __restrict__ inv4, int n) {
    int i = blockIdx.x * 256 + threadIdx.x;
    if (i < n) inv4[i] = 1.0f / (float)max(deg4[i], 1);
}

__global__ __launch_bounds__(256) void block_sum(const int* __restrict__ deg,
                                                 int* __restrict__ bsum, int n) {
    __shared__ int s[256];
    int i = blockIdx.x * 256 + threadIdx.x;
    s[threadIdx.x] = (i < n) ? deg[i] : 0;
    __syncthreads();
    for (int o = 128; o > 0; o >>= 1) {
        if (threadIdx.x < o) s[threadIdx.x] += s[threadIdx.x + o];
        __syncthreads();
    }
    if (threadIdx.x == 0) bsum[blockIdx.x] = s[0];
}

__global__ __launch_bounds__(1024) void scan_bsum(const int* __restrict__ bsum,
                                                  int* __restrict__ boff, int nb) {
    __shared__ int s[1024];
    int t = threadIdx.x;
    int v0 = (t < nb) ? bsum[t] : 0;
    s[t] = v0;
    __syncthreads();
    for (int o = 1; o < 1024; o <<= 1) {
        int v = (t >= o) ? s[t - o] : 0;
        __syncthreads();
        s[t] += v;
        __syncthreads();
    }
    if (t < nb) boff[t] = s[t] - v0;   // exclusive
}

__global__ __launch_bounds__(256) void block_scan_write(
    const int* __restrict__ deg, const int* __restrict__ boff,
    int* __restrict__ row_ptr, int* __restrict__ cursor, int n, int total) {
    __shared__ int s[256];
    int t = threadIdx.x;
    int i = blockIdx.x * 256 + t;
    int v = (i < n) ? deg[i] : 0;
    s[t] = v;
    __syncthreads();
    for (int o = 1; o < 256; o <<= 1) {
        int u = (t >= o) ? s[t - o] : 0;
        __syncthreads();
        s[t] += u;
        __syncthreads();
    }
    int excl = s[t] - v + boff[blockIdx.x];
    if (i < n) { row_ptr[i] = excl; cursor[i] = excl; }
    if (blockIdx.x == 0 && t == 0) row_ptr[n] = total;
}

__global__ void place_edges4(const int* __restrict__ dst, const int* __restrict__ src,
                             const int* __restrict__ rel, int* __restrict__ cursor,
                             int* __restrict__ e_srcs, int E) {
    int e = blockIdx.x * 256 + threadIdx.x;
    if (e < E) {
        int p = atomicAdd(&cursor[dst[e] * 4 + rel[e]], 1);
        e_srcs[p] = src[e];
    }
}

// ---------------------------------------------------------------------------
// Pooling + MLP head
// ---------------------------------------------------------------------------
__global__ __launch_bounds__(256) void pool_kernel(
    const unsigned short* __restrict__ h, const int* __restrict__ batch,
    float* __restrict__ g_feat)
{
    int g = blockIdx.x;
    int t = threadIdx.x;
    __shared__ int s_lo, s_hi;
    if (t == 0) {
        int lo = 0, hi = N_NODES;
        while (lo < hi) { int m = (lo + hi) >> 1; if (batch[m] < g) lo = m + 1; else hi = m; }
        s_lo = lo;
        int lo2 = lo, hi2 = N_NODES;
        while (lo2 < hi2) { int m = (lo2 + hi2) >> 1; if (batch[m] < g + 1) lo2 = m + 1; else hi2 = m; }
        s_hi = lo2;
    }
    __syncthreads();
    int lo = s_lo, hi = s_hi;
    float sum = 0.f, mx = 0.f;   // post-ReLU
    for (int n = lo; n < hi; ++n) {
        float v = bf2f(h[(size_t)n * 256 + t]);
        sum += v;
        mx = fmaxf(mx, v);
    }
    float cnt = (float)(hi - lo);
    g_feat[g * 512 + t]       = sum / fmaxf(cnt, 1.0f);
    g_feat[g * 512 + 256 + t] = (cnt > 0.f) ? mx : 0.f;
}

__global__ __launch_bounds__(128) void mlp_head(
    const float* __restrict__ g_feat,
    const float* __restrict__ fc1_w, const float* __restrict__ fc1_b,
    const float* __restrict__ fc2_w, const float* __restrict__ fc2_b,
    float* __restrict__ out)
{
    __shared__ float gf[512];
    __shared__ float partial[2];
    int g = blockIdx.x, t = threadIdx.x;
    for (int i = t; i < 512; i += 128) gf[i] = g_feat[g * 512 + i];
    __syncthreads();
    float acc = fc1_b[t];
    for (int i = 0; i < 512; ++i) acc += gf[i] * fc1_w[i * 128 + t];
    float h1 = fmaxf(acc, 0.f);
    float v = h1 * fc2_w[t];
    #pragma unroll
    for (int off = 32; off > 0; off >>= 1) v += __shfl_down(v, off);
    if ((t & 63) == 0) partial[t >> 6] = v;
    __syncthreads();
    if (t == 0) {
        float s = partial[0] + partial[1] + fc2_b[0];
        out[g] = 1.0f / (1.0f + expf(-s));
    }
}

// ---------------------------------------------------------------------------
// Launch
// ---------------------------------------------------------------------------
extern "C" void kernel_launch(void* const* d_in, const int* in_sizes, int n_in,
                              void* d_out, int out_size, void* d_ws, size_t ws_size,
                              hipStream_t stream) {
    const float* x          = (const float*)d_in[0];
    const int*   edge_index = (const int*)d_in[1];
    const int*   edge_attr  = (const int*)d_in[2];
    const int*   batch      = (const int*)d_in[3];
    const float* w0         = (const float*)d_in[4];
    const float* root0      = (const float*)d_in[5];
    const float* b0         = (const float*)d_in[6];
    const float* w_rest     = (const float*)d_in[7];
    const float* root_rest  = (const float*)d_in[8];
    const float* b_rest     = (const float*)d_in[9];
    const float* fc1_w      = (const float*)d_in[10];
    const float* fc1_b      = (const float*)d_in[11];
    const float* fc2_w      = (const float*)d_in[12];
    const float* fc2_b      = (const float*)d_in[13];
    float* out = (float*)d_out;

    const int* e_src = edge_index;
    const int* e_dst = edge_index + N_EDGES;

    char* p = (char*)d_ws;
    auto alloc = [&](size_t bytes) { char* q = p; p += (bytes + 255) & ~(size_t)255; return q; };
    unsigned short* x_bf   = (unsigned short*)alloc((size_t)M_PAD * D_IN * 2);   // 92 MB; reused as rootT after L0
    unsigned short* msgbuf = (unsigned short*)alloc((size_t)M_PAD * 1024 * 2);   // 123 MB (4 slabs of 31 MB)
    unsigned short* hA     = (unsigned short*)alloc((size_t)M_PAD * 256 * 2);    // 31 MB
    unsigned short* hB     = (unsigned short*)alloc((size_t)M_PAD * 256 * 2);    // 31 MB
    unsigned short* Wt0    = (unsigned short*)alloc((size_t)N_TOT * D_IN * 2);
    unsigned short* WtR    = (unsigned short*)alloc((size_t)5 * N_TOT * 256 * 2);
    float*          ebias  = (float*)alloc((size_t)6 * N_TOT * 4);
    float*          inv4   = (float*)alloc((size_t)N_NODES * 4 * 4);
    float*          g_feat = (float*)alloc((size_t)N_GRAPHS * 512 * 4);
    int*            deg4   = (int*)alloc((size_t)N_NODES * 4 * 4);
    int*            rp4    = (int*)alloc(((size_t)N_NODES * 4 + 1) * 4);
    int*            cursor4= (int*)alloc((size_t)N_NODES * 4 * 4);
    int*            bsum   = (int*)alloc(1024 * 4);
    int*            boff   = (int*)alloc(1024 * 4);
    int*            e_srcs = (int*)alloc((size_t)N_EDGES * 4);

    const int n4 = N_NODES * 4;                 // 240000
    const int nscan4 = cdiv(n4, 256);           // 938

    // --- prep ---
    hipMemsetAsync(deg4, 0, (size_t)n4 * 4, stream);
    convert_x<<<cdiv(M_PAD * D_IN / 4, 256), 256, 0, stream>>>(x, x_bf);
    pack_w0<<<cdiv(N_TOT * D_IN, 256), 256, 0, stream>>>(root0, w0, Wt0);
    pack_wr<<<cdiv(5 * N_TOT * 256, 256), 256, 0, stream>>>(root_rest, w_rest, WtR);
    build_bias_all<<<cdiv(6 * N_TOT, 256), 256, 0, stream>>>(b0, b_rest, ebias);
    deg4_count<<<cdiv(N_EDGES, 256), 256, 0, stream>>>(e_dst, edge_attr, deg4, N_EDGES);
    invert4<<<cdiv(n4, 256), 256, 0, stream>>>(deg4, inv4, n4);
    block_sum<<<nscan4, 256, 0, stream>>>(deg4, bsum, n4);
    scan_bsum<<<1, 1024, 0, stream>>>(bsum, boff, nscan4);
    block_scan_write<<<nscan4, 256, 0, stream>>>(deg4, boff, rp4, cursor4, n4, N_EDGES);
    place_edges4<<<cdiv(N_EDGES, 256), 256, 0, stream>>>(e_dst, e_src, edge_attr,
                                                         cursor4, e_srcs, N_EDGES);

    // --- layer 0: transform-first GEMM (K=768) + relation-wave aggregate ---
    gemm_l0<<<8 * 295, 512, 0, stream>>>(x_bf, Wt0, ebias, hB, msgbuf, D_IN);
    aggregate_rw<<<N_NODES, 256, 0, stream>>>(hB, msgbuf, rp4, e_srcs, inv4, hA);

    // --- layers 1..5: transform-first (K=256) + relation-wave aggregate ---
    unsigned short* rootT = x_bf;
    unsigned short* cur = hA;
    unsigned short* nxt = hB;
    for (int L = 1; L < N_LAYERS; ++L) {
        gemm_l0<<<8 * 295, 512, 0, stream>>>(
            cur, WtR + (size_t)(L - 1) * N_TOT * 256, ebias + (size_t)L * N_TOT,
            rootT, msgbuf, 256);
        aggregate_rw<<<N_NODES, 256, 0, stream>>>(rootT, msgbuf, rp4, e_srcs, inv4, nxt);
        unsigned short* t = cur; cur = nxt; nxt = t;
    }
    // final h in cur

    pool_kernel<<<N_GRAPHS, 256, 0, stream>>>(cur, batch, g_feat);
    mlp_head<<<N_GRAPHS, 128, 0, stream>>>(g_feat, fc1_w, fc1_b, fc2_w, fc2_b, out);
}

// Round 11
// 1096.805 us; speedup vs baseline: 1.2372x; 1.2372x over previous
//
#include <hip/hip_runtime.h>
#include <hip/hip_bf16.h>

#define N_NODES  60000
#define N_EDGES  240000
#define N_REL    4
#define N_GRAPHS 128
#define D_IN     768
#define D_H      256
#define N_LAYERS 6
#define M_PAD    60032            // 469 * 128
#define N_TOT    1280             // GEMM out: 256 root + 4*256 per-relation msg

static inline int cdiv(int a, int b) { return (a + b - 1) / b; }

typedef __attribute__((ext_vector_type(8))) short short8;
typedef __attribute__((ext_vector_type(4))) float f32x4;

__device__ __forceinline__ float bf2f(unsigned short u) {
    union { unsigned int i; float f; } c; c.i = ((unsigned int)u) << 16; return c.f;
}
__device__ __forceinline__ float bflo(unsigned int u) {
    union { unsigned int i; float f; } c; c.i = u << 16; return c.f;
}
__device__ __forceinline__ float bfhi(unsigned int u) {
    union { unsigned int i; float f; } c; c.i = u & 0xffff0000u; return c.f;
}
__device__ __forceinline__ unsigned short f2bf(float f) {
    union { float f; unsigned int i; } c; c.f = f;
    unsigned int i = c.i;
    unsigned int r = (i + 0x7FFFu + ((i >> 16) & 1u)) >> 16;   // RNE
    return (unsigned short)r;
}

__device__ __forceinline__ void gload16(const void* g, void* l) {
    __builtin_amdgcn_global_load_lds((const __attribute__((address_space(1))) void*)g,
                                     (__attribute__((address_space(3))) void*)l, 16, 0, 0);
}

// ---------------------------------------------------------------------------
// Transform GEMM (proven 128x256 tile, ~154 us @ K=768, ~52 us @ K=256):
// A[M_PAD,K] bf16 @ Wt[1280,K]^T -> root[M,256] (+bias) and per-relation
// msg SLABS msg[r][M,256].  Double-buffered LDS; XCD-chunked remap.
// grid = 8*295 (15 idle).
// ---------------------------------------------------------------------------
__global__ __launch_bounds__(512) void gemm_l0(
    const unsigned short* __restrict__ A,
    const unsigned short* __restrict__ Bt,
    const float* __restrict__ bias,
    unsigned short* __restrict__ out_root,
    unsigned short* __restrict__ out_msg,     // [4][M_PAD][256] slabs
    int K)
{
    __shared__ __align__(16) unsigned short S[2][(128 + 256) * 32];   // 2 x 24576 B

    const int bid  = blockIdx.x;
    const int xcd  = bid & 7;
    const int j    = bid >> 3;                       // 0..294
    const int nrow = (xcd < 5) ? 59 : 58;
    const int rbase = (xcd < 5) ? xcd * 59 : 295 + (xcd - 5) * 58;
    const int rr = j / 5, cc = j % 5;
    if (rr >= nrow) return;
    const int bm = (rbase + rr) * 128;
    const int bn = cc * 256;

    const int tid  = threadIdx.x;
    const int wave = tid >> 6, lane = tid & 63;
    const int wm = (wave & 1) * 64, wn = (wave >> 1) * 64;

    const int lr = lane >> 2;
    const int kg = ((lane & 3) ^ ((lr ^ (lr >> 2)) & 3)) * 8;   // swizzled k-chunk
    const unsigned short* gsrc[3];
    int ldoff[3];
    #pragma unroll
    for (int t = 0; t < 3; ++t) {
        int g = wave * 3 + t;
        if (g < 8) {
            gsrc[t] = A + (size_t)(bm + g * 16 + lr) * K + kg;
            ldoff[t] = g * 512;                       // As region: shorts 0..4095
        } else {
            gsrc[t] = Bt + (size_t)(bn + (g - 8) * 16 + lr) * K + kg;
            ldoff[t] = 4096 + (g - 8) * 512;          // Bs region: shorts 4096..12287
        }
    }

    f32x4 acc[4][4] = {};
    const int fr = lane & 15;
    const int qsw = (((lane >> 4) ^ fr ^ (fr >> 2)) & 3) * 8;

    const int nstep = K >> 5;                         // 24 (L0) or 8 (mid)
    gload16(gsrc[0], S[0] + ldoff[0]);
    gload16(gsrc[1], S[0] + ldoff[1]);
    gload16(gsrc[2], S[0] + ldoff[2]);
    __syncthreads();                                  // slice 0 staged

    #pragma unroll 1
    for (int t = 0; t < nstep; ++t) {
        if (t + 1 < nstep) {                          // stage ahead into alt buffer
            unsigned short* nb = S[(t + 1) & 1];
            gload16(gsrc[0] + (t + 1) * 32, nb + ldoff[0]);
            gload16(gsrc[1] + (t + 1) * 32, nb + ldoff[1]);
            gload16(gsrc[2] + (t + 1) * 32, nb + ldoff[2]);
        }
        const unsigned short* cur = S[t & 1];
        short8 a[4], b[4];
        #pragma unroll
        for (int q = 0; q < 4; ++q) {
            a[q] = *(const short8*)&cur[(wm + q * 16 + fr) * 32 + qsw];
            b[q] = *(const short8*)&cur[4096 + (wn + q * 16 + fr) * 32 + qsw];
        }
        #pragma unroll
        for (int mt = 0; mt < 4; ++mt)
            #pragma unroll
            for (int nt = 0; nt < 4; ++nt)
                acc[mt][nt] = __builtin_amdgcn_mfma_f32_16x16x32_bf16(
                    a[mt], b[nt], acc[mt][nt], 0, 0, 0);
        __syncthreads();   // drains vmcnt(0): stage(t+1) done; reads of S[(t+1)&1] done
    }

    const bool is_root = (bn == 0);   // block-uniform
    #pragma unroll
    for (int mt = 0; mt < 4; ++mt) {
        #pragma unroll
        for (int nt = 0; nt < 4; ++nt) {
            int col = bn + wn + nt * 16 + fr;
            float bv = bias[col];
            #pragma unroll
            for (int r = 0; r < 4; ++r) {
                int row = bm + wm + mt * 16 + ((lane >> 4) << 2) + r;
                float v = acc[mt][nt][r] + bv;
                if (is_root) {
                    out_root[(size_t)row * 256 + col] = f2bf(v);
                } else {
                    int plane = (col >> 8) - 1;                    // relation 0..3
                    out_msg[((size_t)plane * M_PAD + row) * 256 + (col & 255)] = f2bf(v);
                }
            }
        }
    }
}

// ---------------------------------------------------------------------------
// Aggregate, MLP version: one wave per node (4 waves/block, barrier-free,
// grid 15000 — R9's proven shape) but the gather is restructured for
// memory-level parallelism:
//   - all <=64 edge srcs of the node read in ONE coalesced load
//   - single accumulator via sum_e inv_{r(e)} * msg_{r(e)}[src_e]
//   - edges processed 4 at a time with UNCONDITIONAL loads (tail lanes
//     shuffle src 0 -> cached dummy row; contribution zeroed by scale)
//   -> 4 independent 512 B reads in flight per wave instead of a serial
//      dependent chain.  Targets the observed idle-machine latency bound
//      (VALUBusy 3.5%, HBM 124 GB/s).
// ---------------------------------------------------------------------------
__global__ __launch_bounds__(256) void aggregate_mlp(
    const unsigned short* __restrict__ rootb,   // [M_PAD,256]
    const unsigned short* __restrict__ msg,     // [4][M_PAD,256] slabs
    const int* __restrict__ rp4, const int* __restrict__ e_srcs,
    const float* __restrict__ inv4,
    unsigned short* __restrict__ h_out)         // [M_PAD,256]
{
    int node = blockIdx.x * 4 + (threadIdx.x >> 6);
    if (node >= N_NODES) return;
    int lane = threadIdx.x & 63;

    int b0 = rp4[node * 4 + 0];
    int b1 = rp4[node * 4 + 1];
    int b2 = rp4[node * 4 + 2];
    int b3 = rp4[node * 4 + 3];
    int b4 = rp4[node * 4 + 4];
    int nedge = b4 - b0;
    float4 iv = *(const float4*)&inv4[(size_t)node * 4];

    ushort4 rt = *(const ushort4*)&rootb[(size_t)node * 256 + lane * 4];
    float4 acc = make_float4(bf2f(rt.x), bf2f(rt.y), bf2f(rt.z), bf2f(rt.w));

    for (int off = 0; off < nedge; off += 64) {
        int cnt = min(nedge - off, 64);
        int src_l = (lane < cnt) ? e_srcs[b0 + off + lane] : 0;   // coalesced
        #pragma unroll 1
        for (int i = 0; i < cnt; i += 4) {
            int ea = b0 + off + i;
            int s0 = __shfl(src_l, i + 0);
            int s1 = __shfl(src_l, i + 1);
            int s2 = __shfl(src_l, i + 2);
            int s3 = __shfl(src_l, i + 3);
            int p0 = (ea + 0 >= b3) ? 3 : (ea + 0 >= b2) ? 2 : (ea + 0 >= b1) ? 1 : 0;
            int p1 = (ea + 1 >= b3) ? 3 : (ea + 1 >= b2) ? 2 : (ea + 1 >= b1) ? 1 : 0;
            int p2 = (ea + 2 >= b3) ? 3 : (ea + 2 >= b2) ? 2 : (ea + 2 >= b1) ? 1 : 0;
            int p3 = (ea + 3 >= b3) ? 3 : (ea + 3 >= b2) ? 2 : (ea + 3 >= b1) ? 1 : 0;
            // 4 independent loads, always address-valid (tail reads slab row 0)
            ushort4 m0 = *(const ushort4*)&msg[((size_t)p0 * M_PAD + s0) * 256 + lane * 4];
            ushort4 m1 = *(const ushort4*)&msg[((size_t)p1 * M_PAD + s1) * 256 + lane * 4];
            ushort4 m2 = *(const ushort4*)&msg[((size_t)p2 * M_PAD + s2) * 256 + lane * 4];
            ushort4 m3 = *(const ushort4*)&msg[((size_t)p3 * M_PAD + s3) * 256 + lane * 4];
            float f0 = (i + 0 < cnt) ? ((p0 == 0) ? iv.x : (p0 == 1) ? iv.y : (p0 == 2) ? iv.z : iv.w) : 0.f;
            float f1 = (i + 1 < cnt) ? ((p1 == 0) ? iv.x : (p1 == 1) ? iv.y : (p1 == 2) ? iv.z : iv.w) : 0.f;
            float f2 = (i + 2 < cnt) ? ((p2 == 0) ? iv.x : (p2 == 1) ? iv.y : (p2 == 2) ? iv.z : iv.w) : 0.f;
            float f3 = (i + 3 < cnt) ? ((p3 == 0) ? iv.x : (p3 == 1) ? iv.y : (p3 == 2) ? iv.z : iv.w) : 0.f;
            acc.x += f0 * bf2f(m0.x) + f1 * bf2f(m1.x) + f2 * bf2f(m2.x) + f3 * bf2f(m3.x);
            acc.y += f0 * bf2f(m0.y) + f1 * bf2f(m1.y) + f2 * bf2f(m2.y) + f3 * bf2f(m3.y);
            acc.z += f0 * bf2f(m0.z) + f1 * bf2f(m1.z) + f2 * bf2f(m2.z) + f3 * bf2f(m3.z);
            acc.w += f0 * bf2f(m0.w) + f1 * bf2f(m1.w) + f2 * bf2f(m2.w) + f3 * bf2f(m3.w);
        }
    }

    ushort4 o;
    o.x = f2bf(fmaxf(acc.x, 0.f));
    o.y = f2bf(fmaxf(acc.y, 0.f));
    o.z = f2bf(fmaxf(acc.z, 0.f));
    o.w = f2bf(fmaxf(acc.w, 0.f));
    *(ushort4*)&h_out[(size_t)node * 256 + lane * 4] = o;
}

// ---------------------------------------------------------------------------
// Prep kernels
// ---------------------------------------------------------------------------
__global__ void convert_x(const float* __restrict__ x, unsigned short* __restrict__ xb) {
    size_t i = ((size_t)blockIdx.x * 256 + threadIdx.x) * 4;
    if (i >= (size_t)M_PAD * D_IN) return;
    ushort4 o;
    if (i < (size_t)N_NODES * D_IN) {
        float4 v = *(const float4*)&x[i];
        o.x = f2bf(v.x); o.y = f2bf(v.y); o.z = f2bf(v.z); o.w = f2bf(v.w);
    } else {
        o.x = o.y = o.z = o.w = 0;
    }
    *(ushort4*)&xb[i] = o;
}

__global__ void pack_w0(const float* __restrict__ root0, const float* __restrict__ w0,
                        unsigned short* __restrict__ Wt0) {
    int idx = blockIdx.x * 256 + threadIdx.x;            // Wt0[n][k], [1280 x 768]
    if (idx >= N_TOT * D_IN) return;
    int k = idx % D_IN, n = idx / D_IN;
    float v = (n < 256) ? root0[k * 256 + n]
                        : w0[(((n >> 8) - 1) * D_IN + k) * 256 + (n & 255)];
    Wt0[idx] = f2bf(v);
}

// WtR[l][n][k], n in [0,1280), k in [0,256):
//   n<256  -> root_rest[l][k][n]
//   n>=256 -> w_rest[l][(n>>8)-1][k][n&255]
__global__ void pack_wr(const float* __restrict__ root_rest, const float* __restrict__ w_rest,
                        unsigned short* __restrict__ WtR) {
    int idx = blockIdx.x * 256 + threadIdx.x;
    if (idx >= 5 * N_TOT * 256) return;
    int k = idx & 255; int t = idx >> 8; int n = t % N_TOT; int l = t / N_TOT;
    float v = (n < 256)
        ? root_rest[(l * 256 + k) * 256 + n]
        : w_rest[(((l * 4 + ((n >> 8) - 1)) * 256) + k) * 256 + (n & 255)];
    WtR[idx] = f2bf(v);
}

// eb[6][1280]: l=0 -> [b0 | 0...]; l>=1 -> [b_rest[l-1] | 0...]
__global__ void build_bias_all(const float* __restrict__ b0, const float* __restrict__ b_rest,
                               float* __restrict__ eb) {
    int i = blockIdx.x * 256 + threadIdx.x;
    if (i >= 6 * N_TOT) return;
    int l = i / N_TOT, c = i % N_TOT;
    float v = 0.f;
    if (c < 256) v = (l == 0) ? b0[c] : b_rest[(l - 1) * 256 + c];
    eb[i] = v;
}

// ---------------------------------------------------------------------------
// (dst, rel)-sorted CSR over 4*N segments
// ---------------------------------------------------------------------------
__global__ void deg4_count(const int* __restrict__ dst, const int* __restrict__ rel,
                           int* __restrict__ deg4, int E) {
    int e = blockIdx.x * 256 + threadIdx.x;
    if (e < E) atomicAdd(&deg4[dst[e] * 4 + rel[e]], 1);
}

__global__ void invert4(const int* __restrict__ deg4, float* __restrict__ inv4, int n) {
    int i = blockIdx.x * 256 + threadIdx.x;
    if (i < n) inv4[i] = 1.0f / (float)max(deg4[i], 1);
}

__global__ __launch_bounds__(256) void block_sum(const int* __restrict__ deg,
                                                 int* __restrict__ bsum, int n) {
    __shared__ int s[256];
    int i = blockIdx.x * 256 + threadIdx.x;
    s[threadIdx.x] = (i < n) ? deg[i] : 0;
    __syncthreads();
    for (int o = 128; o > 0; o >>= 1) {
        if (threadIdx.x < o) s[threadIdx.x] += s[threadIdx.x + o];
        __syncthreads();
    }
    if (threadIdx.x == 0) bsum[blockIdx.x] = s[0];
}

__global__ __launch_bounds__(1024) void scan_bsum(const int* __restrict__ bsum,
                                                  int* __restrict__ boff, int nb) {
    __shared__ int s[1024];
    int t = threadIdx.x;
    int v0 = (t < nb) ? bsum[t] : 0;
    s[t] = v0;
    __syncthreads();
    for (int o = 1; o < 1024; o <<= 1) {
        int v = (t >= o) ? s[t - o] : 0;
        __syncthreads();
        s[t] += v;
        __syncthreads();
    }
    if (t < nb) boff[t] = s[t] - v0;   // exclusive
}

__global__ __launch_bounds__(256) void block_scan_write(
    const int* __restrict__ deg, const int* __restrict__ boff,
    int* __restrict__ row_ptr, int* __restrict__ cursor, int n, int total) {
    __shared__ int s[256];
    int t = threadIdx.x;
    int i = blockIdx.x * 256 + t;
    int v = (i < n) ? deg[i] : 0;
    s[t] = v;
    __syncthreads();
    for (int o = 1; o < 256; o <<= 1) {
        int u = (t >= o) ? s[t - o] : 0;
        __syncthreads();
        s[t] += u;
        __syncthreads();
    }
    int excl = s[t] - v + boff[blockIdx.x];
    if (i < n) { row_ptr[i] = excl; cursor[i] = excl; }
    if (blockIdx.x == 0 && t == 0) row_ptr[n] = total;
}

__global__ void place_edges4(const int* __restrict__ dst, const int* __restrict__ src,
                             const int* __restrict__ rel, int* __restrict__ cursor,
                             int* __restrict__ e_srcs, int E) {
    int e = blockIdx.x * 256 + threadIdx.x;
    if (e < E) {
        int p = atomicAdd(&cursor[dst[e] * 4 + rel[e]], 1);
        e_srcs[p] = src[e];
    }
}

// ---------------------------------------------------------------------------
// Pooling + MLP head
// ---------------------------------------------------------------------------
__global__ __launch_bounds__(256) void pool_kernel(
    const unsigned short* __restrict__ h, const int* __restrict__ batch,
    float* __restrict__ g_feat)
{
    int g = blockIdx.x;
    int t = threadIdx.x;
    __shared__ int s_lo, s_hi;
    if (t == 0) {
        int lo = 0, hi = N_NODES;
        while (lo < hi) { int m = (lo + hi) >> 1; if (batch[m] < g) lo = m + 1; else hi = m; }
        s_lo = lo;
        int lo2 = lo, hi2 = N_NODES;
        while (lo2 < hi2) { int m = (lo2 + hi2) >> 1; if (batch[m] < g + 1) lo2 = m + 1; else hi2 = m; }
        s_hi = lo2;
    }
    __syncthreads();
    int lo = s_lo, hi = s_hi;
    float sum = 0.f, mx = 0.f;   // post-ReLU
    for (int n = lo; n < hi; ++n) {
        float v = bf2f(h[(size_t)n * 256 + t]);
        sum += v;
        mx = fmaxf(mx, v);
    }
    float cnt = (float)(hi - lo);
    g_feat[g * 512 + t]       = sum / fmaxf(cnt, 1.0f);
    g_feat[g * 512 + 256 + t] = (cnt > 0.f) ? mx : 0.f;
}

__global__ __launch_bounds__(128) void mlp_head(
    const float* __restrict__ g_feat,
    const float* __restrict__ fc1_w, const float* __restrict__ fc1_b,
    const float* __restrict__ fc2_w, const float* __restrict__ fc2_b,
    float* __restrict__ out)
{
    __shared__ float gf[512];
    __shared__ float partial[2];
    int g = blockIdx.x, t = threadIdx.x;
    for (int i = t; i < 512; i += 128) gf[i] = g_feat[g * 512 + i];
    __syncthreads();
    float acc = fc1_b[t];
    for (int i = 0; i < 512; ++i) acc += gf[i] * fc1_w[i * 128 + t];
    float h1 = fmaxf(acc, 0.f);
    float v = h1 * fc2_w[t];
    #pragma unroll
    for (int off = 32; off > 0; off >>= 1) v += __shfl_down(v, off);
    if ((t & 63) == 0) partial[t >> 6] = v;
    __syncthreads();
    if (t == 0) {
        float s = partial[0] + partial[1] + fc2_b[0];
        out[g] = 1.0f / (1.0f + expf(-s));
    }
}

// ---------------------------------------------------------------------------
// Launch
// ---------------------------------------------------------------------------
extern "C" void kernel_launch(void* const* d_in, const int* in_sizes, int n_in,
                              void* d_out, int out_size, void* d_ws, size_t ws_size,
                              hipStream_t stream) {
    const float* x          = (const float*)d_in[0];
    const int*   edge_index = (const int*)d_in[1];
    const int*   edge_attr  = (const int*)d_in[2];
    const int*   batch      = (const int*)d_in[3];
    const float* w0         = (const float*)d_in[4];
    const float* root0      = (const float*)d_in[5];
    const float* b0         = (const float*)d_in[6];
    const float* w_rest     = (const float*)d_in[7];
    const float* root_rest  = (const float*)d_in[8];
    const float* b_rest     = (const float*)d_in[9];
    const float* fc1_w      = (const float*)d_in[10];
    const float* fc1_b      = (const float*)d_in[11];
    const float* fc2_w      = (const float*)d_in[12];
    const float* fc2_b      = (const float*)d_in[13];
    float* out = (float*)d_out;

    const int* e_src = edge_index;
    const int* e_dst = edge_index + N_EDGES;

    char* p = (char*)d_ws;
    auto alloc = [&](size_t bytes) { char* q = p; p += (bytes + 255) & ~(size_t)255; return q; };
    unsigned short* x_bf   = (unsigned short*)alloc((size_t)M_PAD * D_IN * 2);   // 92 MB; reused as rootT after L0
    unsigned short* msgbuf = (unsigned short*)alloc((size_t)M_PAD * 1024 * 2);   // 123 MB (4 slabs of 31 MB)
    unsigned short* hA     = (unsigned short*)alloc((size_t)M_PAD * 256 * 2);    // 31 MB
    unsigned short* hB     = (unsigned short*)alloc((size_t)M_PAD * 256 * 2);    // 31 MB
    unsigned short* Wt0    = (unsigned short*)alloc((size_t)N_TOT * D_IN * 2);
    unsigned short* WtR    = (unsigned short*)alloc((size_t)5 * N_TOT * 256 * 2);
    float*          ebias  = (float*)alloc((size_t)6 * N_TOT * 4);
    float*          inv4   = (float*)alloc((size_t)N_NODES * 4 * 4);
    float*          g_feat = (float*)alloc((size_t)N_GRAPHS * 512 * 4);
    int*            deg4   = (int*)alloc((size_t)N_NODES * 4 * 4);
    int*            rp4    = (int*)alloc(((size_t)N_NODES * 4 + 1) * 4);
    int*            cursor4= (int*)alloc((size_t)N_NODES * 4 * 4);
    int*            bsum   = (int*)alloc(1024 * 4);
    int*            boff   = (int*)alloc(1024 * 4);
    int*            e_srcs = (int*)alloc((size_t)N_EDGES * 4);

    const int n4 = N_NODES * 4;                 // 240000
    const int nscan4 = cdiv(n4, 256);           // 938

    // --- prep ---
    hipMemsetAsync(deg4, 0, (size_t)n4 * 4, stream);
    convert_x<<<cdiv(M_PAD * D_IN / 4, 256), 256, 0, stream>>>(x, x_bf);
    pack_w0<<<cdiv(N_TOT * D_IN, 256), 256, 0, stream>>>(root0, w0, Wt0);
    pack_wr<<<cdiv(5 * N_TOT * 256, 256), 256, 0, stream>>>(root_rest, w_rest, WtR);
    build_bias_all<<<cdiv(6 * N_TOT, 256), 256, 0, stream>>>(b0, b_rest, ebias);
    deg4_count<<<cdiv(N_EDGES, 256), 256, 0, stream>>>(e_dst, edge_attr, deg4, N_EDGES);
    invert4<<<cdiv(n4, 256), 256, 0, stream>>>(deg4, inv4, n4);
    block_sum<<<nscan4, 256, 0, stream>>>(deg4, bsum, n4);
    scan_bsum<<<1, 1024, 0, stream>>>(bsum, boff, nscan4);
    block_scan_write<<<nscan4, 256, 0, stream>>>(deg4, boff, rp4, cursor4, n4, N_EDGES);
    place_edges4<<<cdiv(N_EDGES, 256), 256, 0, stream>>>(e_dst, e_src, edge_attr,
                                                         cursor4, e_srcs, N_EDGES);

    // --- layer 0: transform-first GEMM (K=768) + MLP aggregate ---
    gemm_l0<<<8 * 295, 512, 0, stream>>>(x_bf, Wt0, ebias, hB, msgbuf, D_IN);
    aggregate_mlp<<<cdiv(N_NODES, 4), 256, 0, stream>>>(hB, msgbuf, rp4, e_srcs, inv4, hA);

    // --- layers 1..5: transform-first (K=256) + MLP aggregate ---
    unsigned short* rootT = x_bf;
    unsigned short* cur = hA;
    unsigned short* nxt = hB;
    for (int L = 1; L < N_LAYERS; ++L) {
        gemm_l0<<<8 * 295, 512, 0, stream>>>(
            cur, WtR + (size_t)(L - 1) * N_TOT * 256, ebias + (size_t)L * N_TOT,
            rootT, msgbuf, 256);
        aggregate_mlp<<<cdiv(N_NODES, 4), 256, 0, stream>>>(rootT, msgbuf, rp4, e_srcs, inv4, nxt);
        unsigned short* t = cur; cur = nxt; nxt = t;
    }
    // final h in cur

    pool_kernel<<<N_GRAPHS, 256, 0, stream>>>(cur, batch, g_feat);
    mlp_head<<<N_GRAPHS, 128, 0, stream>>>(g_feat, fc1_w, fc1_b, fc2_w, fc2_b, out);
}